// Round 5
// baseline (366.703 us; speedup 1.0000x reference)
//
#include <hip/hip_runtime.h>
#include <stdint.h>

#define EMB 512
#define THREE_E 1536
#define SL 16384
#define K_DIM 512

typedef unsigned short ushort;
typedef short bf16x8 __attribute__((ext_vector_type(8)));
typedef float f32x4 __attribute__((ext_vector_type(4)));

__device__ __forceinline__ ushort f2bf(float f) {
  unsigned u = __float_as_uint(f);
  u += 0x7fffu + ((u >> 16) & 1u);
  return (ushort)(u >> 16);
}
__device__ __forceinline__ float bf2f(ushort s) {
  return __uint_as_float((unsigned)s << 16);
}

// async global->LDS, 16 B per lane; lds arg must be the wave-uniform base.
__device__ __forceinline__ void async16(const ushort* g, ushort* l) {
  __builtin_amdgcn_global_load_lds(
      (const __attribute__((address_space(1))) unsigned int*)g,
      (__attribute__((address_space(3))) unsigned int*)l, 16, 0, 0);
}

// ---------------- W fp32 -> bf16 ----------------
__global__ __launch_bounds__(256) void wconv(const float* __restrict__ W,
                                             ushort* __restrict__ Wb) {
  int i = blockIdx.x * 256 + threadIdx.x;
  float4 f = ((const float4*)W)[i];
  uint2 o;
  o.x = (unsigned)f2bf(f.x) | ((unsigned)f2bf(f.y) << 16);
  o.y = (unsigned)f2bf(f.z) | ((unsigned)f2bf(f.w) << 16);
  ((uint2*)Wb)[i] = o;
}

// ---------------- x [B,E,S,L] fp32 -> xT [B, S*L, E] bf16 (vectorized) ----------------
__global__ __launch_bounds__(256) void xpose(const float* __restrict__ x,
                                             ushort* __restrict__ xT) {
  __shared__ ushort t[64][68];  // 68-pad: 8B-aligned rows, modest conflict on column reads
  int b = blockIdx.z;
  int i0 = blockIdx.y * 64;
  int n0 = blockIdx.x * 64;
  int tid = threadIdx.x;
  const float* xp = x + ((size_t)(b * EMB + i0)) * SL + n0;
  #pragma unroll
  for (int it = 0; it < 4; it++) {
    int f = it * 256 + tid;
    int r = f >> 4, c4 = (f & 15) * 4;
    float4 v = *(const float4*)&xp[(size_t)r * SL + c4];
    uint2 p;
    p.x = (unsigned)f2bf(v.x) | ((unsigned)f2bf(v.y) << 16);
    p.y = (unsigned)f2bf(v.z) | ((unsigned)f2bf(v.w) << 16);
    *(uint2*)&t[r][c4] = p;
  }
  __syncthreads();
  ushort* op = xT + ((size_t)(b * SL + n0)) * EMB + i0;
  #pragma unroll
  for (int it = 0; it < 4; it++) {
    int u = it * 256 + tid;
    int n = u >> 4, i4 = (u & 15) * 4;
    uint2 p;
    ushort* ps = (ushort*)&p;
    #pragma unroll
    for (int j = 0; j < 4; j++) ps[j] = t[i4 + j][n];
    *(uint2*)&op[(size_t)n * EMB + i4] = p;
  }
}

// ---------------- QKV GEMM: barrier-free K-loop, fragments direct global->VGPR ----------------
// W (1.5 MB bf16) is L2-resident on every XCD; each block's xT panel (128 KB) is pinned to one
// XCD L2 via dispatch-id decode (xcd = wg&7 = n_panel&7, m fastest within panel -> 12 consecutive
// same-XCD blocks reuse the panel). MFMA A/B fragments are 16 B of contiguous k per lane
// (row-major [row][k] for both W and xT), so each wave-load touches 16 fully-consumed 64B lines.
// NO LDS staging, NO barriers, NO waitcnt in the K-loop: waves stream independently, the
// scheduler interleaves MFMA with loads freely. LDS = epilogue scratch only (34816 B).
__global__ __launch_bounds__(256, 3) void qkv_gemm(const ushort* __restrict__ Wb,
                                                   const ushort* __restrict__ xT,
                                                   const float* __restrict__ bias,
                                                   ushort* __restrict__ rowQ) {
  __shared__ __align__(16) char sm[34816];
  const int tid = threadIdx.x;
  // ---- dispatch decode: wg&7 = XCD = n_panel&7; within XCD, m fastest ----
  const int wg = blockIdx.x;
  const int xcd = wg & 7;
  const int q = wg >> 3;          // 0..383 per-XCD sequence
  const int b = q / 192;          // batch
  const int r = q - b * 192;      // 0..191
  const int npan = (r / 12) * 8 + xcd;  // 0..127
  const int m = r % 12;           // 0..11
  const int m0 = m * 128;
  const int n0 = npan * 128;
  const int lane = tid & 63;
  const int w = tid >> 6;
  const int wr = (w >> 1) * 64;
  const int wc = (w & 1) * 64;
  const int l15 = lane & 15;
  const int quad = lane >> 4;
  // row pointers for direct fragment loads (k advances via immediate offsets)
  const ushort* ap[4];
  const ushort* bp[4];
  #pragma unroll
  for (int mt = 0; mt < 4; mt++)
    ap[mt] = Wb + (size_t)(m0 + wr + mt * 16 + l15) * K_DIM + quad * 8;
  #pragma unroll
  for (int nt = 0; nt < 4; nt++)
    bp[nt] = xT + ((size_t)b * SL + n0 + wc + nt * 16 + l15) * K_DIM + quad * 8;

  f32x4 acc[4][4] = {};
  bf16x8 af[2][4], bf[2][4];
  // prologue: fragments for k-step 0
  #pragma unroll
  for (int mt = 0; mt < 4; mt++) af[0][mt] = *(const bf16x8*)(ap[mt]);
  #pragma unroll
  for (int nt = 0; nt < 4; nt++) bf[0][nt] = *(const bf16x8*)(bp[nt]);

  #pragma unroll
  for (int s = 0; s < 16; s++) {
    const int cur = s & 1, nxt = cur ^ 1;
    if (s < 15) {
      #pragma unroll
      for (int mt = 0; mt < 4; mt++) af[nxt][mt] = *(const bf16x8*)(ap[mt] + (s + 1) * 32);
      #pragma unroll
      for (int nt = 0; nt < 4; nt++) bf[nxt][nt] = *(const bf16x8*)(bp[nt] + (s + 1) * 32);
    }
    __builtin_amdgcn_s_setprio(1);
    #pragma unroll
    for (int mt = 0; mt < 4; mt++)
      #pragma unroll
      for (int nt = 0; nt < 4; nt++)
        acc[mt][nt] = __builtin_amdgcn_mfma_f32_16x16x32_bf16(af[cur][mt], bf[cur][nt],
                                                              acc[mt][nt], 0, 0, 0);
    __builtin_amdgcn_s_setprio(0);
  }

  // ---- epilogue (verified layout; s-index = n-panel) ----
  __syncthreads();
  {
    ushort* epi = (ushort*)sm;
    const float sc = (m0 < EMB) ? 0.125f : 1.0f;
    const int q4r = quad * 4;
    #pragma unroll
    for (int mt = 0; mt < 4; mt++) {
      int mb = wr + mt * 16 + q4r;
      float b0 = bias[m0 + mb], b1 = bias[m0 + mb + 1];
      float b2 = bias[m0 + mb + 2], b3 = bias[m0 + mb + 3];
      #pragma unroll
      for (int nt = 0; nt < 4; nt++) {
        int l = wc + nt * 16 + l15;
        unsigned u0 = f2bf((acc[mt][nt][0] + b0) * sc);
        unsigned u1 = f2bf((acc[mt][nt][1] + b1) * sc);
        unsigned u2 = f2bf((acc[mt][nt][2] + b2) * sc);
        unsigned u3 = f2bf((acc[mt][nt][3] + b3) * sc);
        uint2 pk;
        pk.x = u0 | (u1 << 16);
        pk.y = u2 | (u3 << 16);
        *(uint2*)&epi[l * 136 + mb] = pk;
      }
    }
  }
  __syncthreads();
  {
    const ushort* epi = (const ushort*)sm;
    const int sel = m0 >> 9;
    const int hb = (m0 & 511) >> 6;
    const int s = n0 >> 7;
    #pragma unroll
    for (int it = 0; it < 8; it++) {
      int flat = it * 2048 + tid * 8;
      int head = flat >> 13;
      int rem = flat & 8191;
      int l = rem >> 6;
      int dd = rem & 63;
      size_t dst = ((((size_t)(b * 3 + sel) * 8 + hb + head) * 128 + s) * 128 + l) * 64 + dd;
      *(uint4*)&rowQ[dst] = *(const uint4*)&epi[l * 136 + head * 64 + dd];
    }
  }
}

// ---------------- barrier-light MFMA axial attention ----------------
// COL=1: block=(l,h,b), queries over s. Writes tmp [b][h][l][s][d] bf16.
// COL=0: block=(s,h,b), queries over l. Adds tmp, writes out fp32 (O^T via swapped MFMA operands).
// LDS: Ks 16K (async, xor-swizzled) + Vt 17K + Ps 17K = 50 KB -> 3 blocks/CU. ONE __syncthreads.
template <int COL>
__global__ __launch_bounds__(256) void attn3(const ushort* __restrict__ qkv,
                                             ushort* __restrict__ tmp,
                                             float* __restrict__ out) {
  __shared__ ushort Ks[128 * 64];   // [t][64d], chunk-xor-swizzled
  __shared__ ushort Vt[64 * 136];   // [d][128t pad8]
  __shared__ ushort Ps[64 * 136];   // [q][128t pad8], wave-private rows
  const int tid = threadIdx.x;
  const int fixed = blockIdx.x;
  const int h = blockIdx.y, b = blockIdx.z;
  const int w = tid >> 6, lane = tid & 63, l15 = lane & 15, quad = lane >> 4;
  const size_t off = COL ? (size_t)fixed * 64 : (size_t)fixed * 8192;
  const size_t tstr = COL ? 8192 : 64;
  const ushort* Qg = qkv + ((size_t)(b * 3 + 0) * 8 + h) * 1048576 + off;
  const ushort* Kg = Qg + (size_t)8 * 1048576;
  const ushort* Vg = Qg + (size_t)16 * 1048576;
  ushort* tb = tmp + (size_t)(b * 8 + h) * 1048576;
  // ---- K: async global->LDS, xor chunk swizzle ----
  {
    int r8k = lane >> 3;
    int cgk = (lane & 7) ^ r8k;
    #pragma unroll
    for (int t = 0; t < 4; t++) {
      int seg = 4 * w + t;
      int row = seg * 8 + r8k;
      async16(&Kg[(size_t)row * tstr + cgk * 8], &Ks[seg * 512]);
    }
  }
  // ---- V: manual transposed stage (rotated scatter, conflict-free) ----
  {
    int trow = tid >> 3, d0 = (tid & 7) * 8, dg = tid & 7;
    #pragma unroll
    for (int it = 0; it < 4; it++) {
      int t = trow + it * 32;
      uint4 vv = *(const uint4*)&Vg[(size_t)t * tstr + d0];
      ushort* vs = (ushort*)&vv;
      #pragma unroll
      for (int k = 0; k < 8; k++) {
        int i = (k + dg) & 7;
        Vt[(d0 + i) * 136 + t] = vs[i];
      }
    }
  }
  // ---- Q fragments (wave-private): direct global->reg, both chunks ----
  bf16x8 aq[2][2];
  #pragma unroll
  for (int c = 0; c < 2; c++) {
    const ushort* qp = Qg + (size_t)(c * 64 + w * 16 + l15) * tstr + quad * 8;
    aq[c][0] = *(const bf16x8*)qp;
    aq[c][1] = *(const bf16x8*)(qp + 32);
  }
  // ---- row pass: prefetch col-pass partials (lane q = w*16+l15, d = mt*16+quad*4..+3) ----
  uint2 treg[2][4];
  if (!COL) {
    #pragma unroll
    for (int c = 0; c < 2; c++) {
      const ushort* tp = tb + (size_t)(c * 64 + w * 16 + l15) * 8192 + (size_t)fixed * 64 + quad * 4;
      #pragma unroll
      for (int mt = 0; mt < 4; mt++) treg[c][mt] = *(const uint2*)(tp + mt * 16);
    }
  }
  __syncthreads();  // the ONLY block barrier
  const int rx = l15 & 7;
  #pragma unroll
  for (int c = 0; c < 2; c++) {
    // ---- S = Q K^T ----
    f32x4 accS[8];
    #pragma unroll
    for (int nt = 0; nt < 8; nt++) {
      int row = nt * 16 + l15;
      bf16x8 bk0 = *(const bf16x8*)&Ks[row * 64 + ((quad ^ rx) * 8)];
      bf16x8 bk1 = *(const bf16x8*)&Ks[row * 64 + (((quad + 4) ^ rx) * 8)];
      f32x4 z = {0.f, 0.f, 0.f, 0.f};
      z = __builtin_amdgcn_mfma_f32_16x16x32_bf16(aq[c][0], bk0, z, 0, 0, 0);
      z = __builtin_amdgcn_mfma_f32_16x16x32_bf16(aq[c][1], bk1, z, 0, 0, 0);
      accS[nt] = z;
    }
    // ---- softmax over t; fold 1/l into P ----
    float inv[4];
    #pragma unroll
    for (int r = 0; r < 4; r++) {
      float mx = accS[0][r];
      #pragma unroll
      for (int nt = 1; nt < 8; nt++) mx = fmaxf(mx, accS[nt][r]);
      mx = fmaxf(mx, __shfl_xor(mx, 1));
      mx = fmaxf(mx, __shfl_xor(mx, 2));
      mx = fmaxf(mx, __shfl_xor(mx, 4));
      mx = fmaxf(mx, __shfl_xor(mx, 8));
      float s = 0.f;
      #pragma unroll
      for (int nt = 0; nt < 8; nt++) {
        float p = __builtin_amdgcn_exp2f((accS[nt][r] - mx) * 1.44269504088896f);
        accS[nt][r] = p;
        s += p;
      }
      s += __shfl_xor(s, 1);
      s += __shfl_xor(s, 2);
      s += __shfl_xor(s, 4);
      s += __shfl_xor(s, 8);
      inv[r] = 1.0f / s;
    }
    // ---- P -> LDS (wave-private rows; wave-level ordering only) ----
    asm volatile("s_waitcnt lgkmcnt(0)" ::: "memory");  // prior chunk's Ps reads retired
    #pragma unroll
    for (int nt = 0; nt < 8; nt++)
      #pragma unroll
      for (int r = 0; r < 4; r++)
        Ps[(w * 16 + quad * 4 + r) * 136 + nt * 16 + l15] = f2bf(accS[nt][r] * inv[r]);
    asm volatile("s_waitcnt lgkmcnt(0)" ::: "memory");  // Ps writes visible to own wave
    // ---- O = P V  (COL: C[q][d])   or   O^T = V^T P^T  (ROW: C[d][q]) ----
    f32x4 accO[4] = {{0.f,0.f,0.f,0.f},{0.f,0.f,0.f,0.f},{0.f,0.f,0.f,0.f},{0.f,0.f,0.f,0.f}};
    #pragma unroll
    for (int kf = 0; kf < 4; kf++) {
      bf16x8 p = *(const bf16x8*)&Ps[(w * 16 + l15) * 136 + kf * 32 + quad * 8];
      #pragma unroll
      for (int t4 = 0; t4 < 4; t4++) {
        bf16x8 v = *(const bf16x8*)&Vt[(t4 * 16 + l15) * 136 + kf * 32 + quad * 8];
        accO[t4] = COL ? __builtin_amdgcn_mfma_f32_16x16x32_bf16(p, v, accO[t4], 0, 0, 0)
                       : __builtin_amdgcn_mfma_f32_16x16x32_bf16(v, p, accO[t4], 0, 0, 0);
      }
    }
    if (COL) {
      // lane holds (q = w*16+quad*4+r, d = t4*16+l15): 32 B-coalesced bf16 runs
      ushort* tp = tb + (size_t)fixed * 8192 + c * 4096;
      #pragma unroll
      for (int t4 = 0; t4 < 4; t4++)
        #pragma unroll
        for (int r = 0; r < 4; r++)
          tp[(w * 16 + quad * 4 + r) * 64 + t4 * 16 + l15] = f2bf(accO[t4][r]);
    } else {
      // lane holds (d = t4*16+quad*4+r, q = w*16+l15): 64 B-coalesced fp32 runs
      float* ob = out + (size_t)(b * EMB + h * 64) * SL + (size_t)fixed * 128 + c * 64 + w * 16 + l15;
      #pragma unroll
      for (int t4 = 0; t4 < 4; t4++) {
        const ushort* tr = (const ushort*)&treg[c][t4];
        #pragma unroll
        for (int r = 0; r < 4; r++)
          ob[(size_t)(t4 * 16 + quad * 4 + r) * SL] = accO[t4][r] + bf2f(tr[r]);
      }
    }
  }
}

extern "C" void kernel_launch(void* const* d_in, const int* in_sizes, int n_in,
                              void* d_out, int out_size, void* d_ws, size_t ws_size,
                              hipStream_t stream) {
  const float* x = (const float*)d_in[0];
  const float* W = (const float*)d_in[1];
  const float* bias = (const float*)d_in[2];
  float* out = (float*)d_out;
  ushort* rowQ = (ushort*)d_ws;
  ushort* xT = (ushort*)((char*)d_ws + 100663296);
  ushort* tmp = (ushort*)((char*)d_ws + 100663296);
  ushort* Wb = (ushort*)((char*)d_ws + 134217728);

  hipLaunchKernelGGL(wconv, dim3(768), dim3(256), 0, stream, W, Wb);
  hipLaunchKernelGGL(xpose, dim3(256, 8, 2), dim3(256), 0, stream, x, xT);
  hipLaunchKernelGGL(qkv_gemm, dim3(3072), dim3(256), 0, stream, Wb, xT, bias, rowQ);
  hipLaunchKernelGGL(attn3<1>, dim3(128, 8, 2), dim3(256), 0, stream, rowQ, tmp, out);
  hipLaunchKernelGGL(attn3<0>, dim3(128, 8, 2), dim3(256), 0, stream, rowQ, tmp, out);
}

// Round 7
// 248.604 us; speedup vs baseline: 1.4750x; 1.4750x over previous
//
#include <hip/hip_runtime.h>
#include <stdint.h>

#define EMB 512
#define THREE_E 1536
#define SL 16384
#define K_DIM 512

typedef unsigned short ushort;
typedef short bf16x8 __attribute__((ext_vector_type(8)));
typedef float f32x4 __attribute__((ext_vector_type(4)));

__device__ __forceinline__ ushort f2bf(float f) {
  unsigned u = __float_as_uint(f);
  u += 0x7fffu + ((u >> 16) & 1u);
  return (ushort)(u >> 16);
}
__device__ __forceinline__ float bf2f(ushort s) {
  return __uint_as_float((unsigned)s << 16);
}

// async global->LDS, 16 B per lane; lds arg must be the wave-uniform base.
__device__ __forceinline__ void async16(const ushort* g, ushort* l) {
  __builtin_amdgcn_global_load_lds(
      (const __attribute__((address_space(1))) unsigned int*)g,
      (__attribute__((address_space(3))) unsigned int*)l, 16, 0, 0);
}

// ---------------- prep: W fp32->bf16 (blocks 0..767) + x transpose (blocks 768..4863) --------
__global__ __launch_bounds__(256) void prep(const float* __restrict__ W,
                                            ushort* __restrict__ Wb,
                                            const float* __restrict__ x,
                                            ushort* __restrict__ xT) {
  __shared__ ushort t[64][68];
  const int bx = blockIdx.x;
  const int tid = threadIdx.x;
  if (bx < 768) {
    int i = bx * 256 + tid;
    float4 f = ((const float4*)W)[i];
    uint2 o;
    o.x = (unsigned)f2bf(f.x) | ((unsigned)f2bf(f.y) << 16);
    o.y = (unsigned)f2bf(f.z) | ((unsigned)f2bf(f.w) << 16);
    ((uint2*)Wb)[i] = o;
    return;
  }
  const int r = bx - 768;              // 0..4095
  const int n0 = (r & 255) * 64;       // SL tile
  const int i0 = ((r >> 8) & 7) * 64;  // E tile
  const int b = r >> 11;               // batch
  const float* xp = x + ((size_t)(b * EMB + i0)) * SL + n0;
  #pragma unroll
  for (int it = 0; it < 4; it++) {
    int f = it * 256 + tid;
    int rr = f >> 4, c4 = (f & 15) * 4;
    float4 v = *(const float4*)&xp[(size_t)rr * SL + c4];
    uint2 p;
    p.x = (unsigned)f2bf(v.x) | ((unsigned)f2bf(v.y) << 16);
    p.y = (unsigned)f2bf(v.z) | ((unsigned)f2bf(v.w) << 16);
    *(uint2*)&t[rr][c4] = p;
  }
  __syncthreads();
  ushort* op = xT + ((size_t)(b * SL + n0)) * EMB + i0;
  #pragma unroll
  for (int it = 0; it < 4; it++) {
    int u = it * 256 + tid;
    int n = u >> 4, i4 = (u & 15) * 4;
    uint2 p;
    ushort* ps = (ushort*)&p;
    #pragma unroll
    for (int j = 0; j < 4; j++) ps[j] = t[i4 + j][n];
    *(uint2*)&op[(size_t)n * EMB + i4] = p;
  }
}

// ---------------- QKV GEMM: 256x256 tile, BK=64, 8-wave, 8-phase counted-vmcnt (R1, 66 us) ----
__global__ __launch_bounds__(512, 2) void qkv_gemm(const ushort* __restrict__ Wb,
                                                   const ushort* __restrict__ xT,
                                                   const float* __restrict__ bias,
                                                   ushort* __restrict__ rowQ) {
  __shared__ __align__(16) char sm[131072];
  ushort* const A0 = (ushort*)sm;
  ushort* const B0 = (ushort*)(sm + 32768);
  ushort* const A1 = (ushort*)(sm + 65536);
  ushort* const B1 = (ushort*)(sm + 98304);
  const int tid = threadIdx.x;
  const int bz = blockIdx.z;
  const int m0 = blockIdx.y * 256;
  const int n0 = blockIdx.x * 256;
  const int lane = tid & 63, w = tid >> 6;
  const int wm = w >> 2, wn = w & 3;
  const int l15 = lane & 15, quad = lane >> 4;
  const int r8 = lane >> 3;
  const int cg8 = ((lane & 7) ^ r8) * 8;
  const int rx = l15 & 7;
  const ushort* Wt = Wb + (size_t)m0 * K_DIM;
  const ushort* Xt = xT + ((size_t)bz * SL + n0) * K_DIM;

  f32x4 acc[8][4] = {};
  bf16x8 av[4][2], bv0[2][2], bv1[2][2];

#define STG(gb, lb)                                                       \
  async16((gb) + (size_t)(w * 8 + r8) * K_DIM + cg8, (lb) + w * 512);     \
  async16((gb) + (size_t)(w * 8 + r8 + 64) * K_DIM + cg8, (lb) + w * 512 + 4096)

#define LDA(AP, MH)                                                           \
  _Pragma("unroll") for (int mt = 0; mt < 4; mt++) {                          \
    const int row = wm * 128 + (MH) * 64 + mt * 16 + l15;                     \
    av[mt][0] = *(const bf16x8*)&(AP)[row * 64 + ((quad ^ rx) * 8)];          \
    av[mt][1] = *(const bf16x8*)&(AP)[row * 64 + (((quad + 4) ^ rx) * 8)];    \
  }

#define LDB(BP, NH, BV)                                                       \
  _Pragma("unroll") for (int nt = 0; nt < 2; nt++) {                          \
    const int row = wn * 64 + (NH) * 32 + nt * 16 + l15;                      \
    BV[nt][0] = *(const bf16x8*)&(BP)[row * 64 + ((quad ^ rx) * 8)];          \
    BV[nt][1] = *(const bf16x8*)&(BP)[row * 64 + (((quad + 4) ^ rx) * 8)];    \
  }

#define MM(MH, NH, BV)                                                        \
  __builtin_amdgcn_s_setprio(1);                                              \
  _Pragma("unroll") for (int mt = 0; mt < 4; mt++)                            \
  _Pragma("unroll") for (int nt = 0; nt < 2; nt++) {                          \
    acc[(MH) * 4 + mt][(NH) * 2 + nt] =                                       \
        __builtin_amdgcn_mfma_f32_16x16x32_bf16(                              \
            av[mt][0], BV[nt][0], acc[(MH) * 4 + mt][(NH) * 2 + nt], 0, 0, 0);\
    acc[(MH) * 4 + mt][(NH) * 2 + nt] =                                       \
        __builtin_amdgcn_mfma_f32_16x16x32_bf16(                              \
            av[mt][1], BV[nt][1], acc[(MH) * 4 + mt][(NH) * 2 + nt], 0, 0, 0);\
  }                                                                           \
  __builtin_amdgcn_s_setprio(0)

#define BAR __builtin_amdgcn_s_barrier()
#define LGKM0 asm volatile("s_waitcnt lgkmcnt(0)" ::: "memory")
#define VMC(N) asm volatile("s_waitcnt vmcnt(" #N ")" ::: "memory")

  STG(Xt, B0);
  STG(Xt + 65536, B0 + 8192);
  STG(Wt, A0);
  STG(Wt + 65536, A0 + 8192);
  STG(Xt + 64, B1);
  STG(Xt + 65536 + 64, B1 + 8192);
  VMC(4);
  BAR;

  for (int t = 0; t < 4; ++t) {
    const int kB = t * 128 + 64;
    const int kN = t * 128 + 128;
    const int kN2 = t * 128 + 192;
    const bool st = (t < 3);
    LDA(A0, 0); LDB(B0, 0, bv0);
    STG(Wt + kB, A1);
    BAR; LGKM0; MM(0, 0, bv0); BAR;
    LDB(B0, 1, bv1);
    STG(Wt + 65536 + kB, A1 + 8192);
    BAR; LGKM0; MM(0, 1, bv1); BAR;
    LDA(A0, 1);
    if (st) { STG(Xt + kN, B0); }
    BAR; LGKM0; MM(1, 1, bv1); BAR;
    if (st) { STG(Xt + 65536 + kN, B0 + 8192); }
    BAR; MM(1, 0, bv0);
    if (t == 3) { VMC(0); } else { VMC(4); }
    BAR;
    LDA(A1, 0); LDB(B1, 0, bv0);
    if (st) { STG(Wt + kN, A0); }
    BAR; LGKM0; MM(0, 0, bv0); BAR;
    LDB(B1, 1, bv1);
    if (st) { STG(Wt + 65536 + kN, A0 + 8192); }
    BAR; LGKM0; MM(0, 1, bv1); BAR;
    LDA(A1, 1);
    if (st) { STG(Xt + kN2, B1); }
    BAR; LGKM0; MM(1, 1, bv1); BAR;
    if (st) { STG(Xt + 65536 + kN2, B1 + 8192); }
    BAR; MM(1, 0, bv0);
    if (st) { VMC(4); }
    BAR;
  }

  __syncthreads();
  {
    ushort* ep = (ushort*)sm + w * 4608;
    const float sc = (m0 < 512) ? 0.125f : 1.0f;
    const int q4 = quad * 4;
    const int sidx = (n0 >> 7) + (wn >> 1);
    const int lbase = (wn & 1) * 64;
    const int ml = (lane & 7) * 8;
    const int nlo = lane >> 3;
    #pragma unroll
    for (int mh = 0; mh < 2; ++mh) {
      if (mh) { LGKM0; }
      #pragma unroll
      for (int mt = 0; mt < 4; ++mt) {
        const int mloc = mt * 16 + q4;
        const int mg = m0 + wm * 128 + mh * 64 + mloc;
        const float b0 = bias[mg], b1 = bias[mg + 1];
        const float b2 = bias[mg + 2], b3 = bias[mg + 3];
        #pragma unroll
        for (int nt = 0; nt < 4; ++nt) {
          const f32x4 a = acc[mh * 4 + mt][nt];
          uint2 pk;
          pk.x = (unsigned)f2bf((a[0] + b0) * sc) | ((unsigned)f2bf((a[1] + b1) * sc) << 16);
          pk.y = (unsigned)f2bf((a[2] + b2) * sc) | ((unsigned)f2bf((a[3] + b3) * sc) << 16);
          *(uint2*)&ep[(nt * 16 + l15) * 72 + mloc] = pk;
        }
      }
      LGKM0;
      const int mb0 = m0 + wm * 128 + mh * 64;
      const int sel = mb0 >> 9;
      const int hh = (mb0 >> 6) & 7;
      ushort* db = rowQ + ((((size_t)(bz * 3 + sel) * 8 + hh) * 128 + sidx) * 128) * 64;
      #pragma unroll
      for (int it = 0; it < 8; ++it) {
        const int nl = it * 8 + nlo;
        *(uint4*)&db[(size_t)(lbase + nl) * 64 + ml] = *(const uint4*)&ep[nl * 72 + ml];
      }
    }
  }
#undef STG
#undef LDA
#undef LDB
#undef MM
#undef BAR
#undef LGKM0
#undef VMC
}

// ---------------- barrier-light MFMA axial attention (verified split kernels) ----------------
// COL=1: block=(l,h,b), queries over s. Writes tmp [b][h][l][s][d] bf16.
// COL=0: block=(s,h,b), queries over l. Adds tmp, writes out fp32 (O^T via swapped MFMA operands).
// Kernel boundary between the two passes is the cross-XCD coherence point (G16) — do NOT fuse
// without explicit agent-scope wb/inv fences (R6 failed exactly here).
template <int COL>
__global__ __launch_bounds__(256) void attn3(const ushort* __restrict__ qkv,
                                             ushort* __restrict__ tmp,
                                             float* __restrict__ out) {
  __shared__ ushort Ks[128 * 64];   // [t][64d], chunk-xor-swizzled
  __shared__ ushort Vt[64 * 136];   // [d][128t pad8]
  __shared__ ushort Ps[64 * 136];   // [q][128t pad8], wave-private rows
  const int tid = threadIdx.x;
  const int fixed = blockIdx.x;
  const int h = blockIdx.y, b = blockIdx.z;
  const int w = tid >> 6, lane = tid & 63, l15 = lane & 15, quad = lane >> 4;
  const size_t off = COL ? (size_t)fixed * 64 : (size_t)fixed * 8192;
  const size_t tstr = COL ? 8192 : 64;
  const ushort* Qg = qkv + ((size_t)(b * 3 + 0) * 8 + h) * 1048576 + off;
  const ushort* Kg = Qg + (size_t)8 * 1048576;
  const ushort* Vg = Qg + (size_t)16 * 1048576;
  ushort* tb = tmp + (size_t)(b * 8 + h) * 1048576;
  // ---- K: async global->LDS, xor chunk swizzle ----
  {
    int r8k = lane >> 3;
    int cgk = (lane & 7) ^ r8k;
    #pragma unroll
    for (int t = 0; t < 4; t++) {
      int seg = 4 * w + t;
      int row = seg * 8 + r8k;
      async16(&Kg[(size_t)row * tstr + cgk * 8], &Ks[seg * 512]);
    }
  }
  // ---- V: manual transposed stage (rotated scatter, conflict-free) ----
  {
    int trow = tid >> 3, d0 = (tid & 7) * 8, dg = tid & 7;
    #pragma unroll
    for (int it = 0; it < 4; it++) {
      int t = trow + it * 32;
      uint4 vv = *(const uint4*)&Vg[(size_t)t * tstr + d0];
      ushort* vs = (ushort*)&vv;
      #pragma unroll
      for (int k = 0; k < 8; k++) {
        int i = (k + dg) & 7;
        Vt[(d0 + i) * 136 + t] = vs[i];
      }
    }
  }
  // ---- Q fragments (wave-private): direct global->reg, both chunks ----
  bf16x8 aq[2][2];
  #pragma unroll
  for (int c = 0; c < 2; c++) {
    const ushort* qp = Qg + (size_t)(c * 64 + w * 16 + l15) * tstr + quad * 8;
    aq[c][0] = *(const bf16x8*)qp;
    aq[c][1] = *(const bf16x8*)(qp + 32);
  }
  // ---- row pass: prefetch col-pass partials (lane q = w*16+l15, d = mt*16+quad*4..+3) ----
  uint2 treg[2][4];
  if (!COL) {
    #pragma unroll
    for (int c = 0; c < 2; c++) {
      const ushort* tp = tb + (size_t)(c * 64 + w * 16 + l15) * 8192 + (size_t)fixed * 64 + quad * 4;
      #pragma unroll
      for (int mt = 0; mt < 4; mt++) treg[c][mt] = *(const uint2*)(tp + mt * 16);
    }
  }
  __syncthreads();  // the ONLY block barrier
  const int rx = l15 & 7;
  #pragma unroll
  for (int c = 0; c < 2; c++) {
    // ---- S = Q K^T ----
    f32x4 accS[8];
    #pragma unroll
    for (int nt = 0; nt < 8; nt++) {
      int row = nt * 16 + l15;
      bf16x8 bk0 = *(const bf16x8*)&Ks[row * 64 + ((quad ^ rx) * 8)];
      bf16x8 bk1 = *(const bf16x8*)&Ks[row * 64 + (((quad + 4) ^ rx) * 8)];
      f32x4 z = {0.f, 0.f, 0.f, 0.f};
      z = __builtin_amdgcn_mfma_f32_16x16x32_bf16(aq[c][0], bk0, z, 0, 0, 0);
      z = __builtin_amdgcn_mfma_f32_16x16x32_bf16(aq[c][1], bk1, z, 0, 0, 0);
      accS[nt] = z;
    }
    // ---- softmax over t; fold 1/l into P ----
    float inv[4];
    #pragma unroll
    for (int r = 0; r < 4; r++) {
      float mx = accS[0][r];
      #pragma unroll
      for (int nt = 1; nt < 8; nt++) mx = fmaxf(mx, accS[nt][r]);
      mx = fmaxf(mx, __shfl_xor(mx, 1));
      mx = fmaxf(mx, __shfl_xor(mx, 2));
      mx = fmaxf(mx, __shfl_xor(mx, 4));
      mx = fmaxf(mx, __shfl_xor(mx, 8));
      float s = 0.f;
      #pragma unroll
      for (int nt = 0; nt < 8; nt++) {
        float p = __builtin_amdgcn_exp2f((accS[nt][r] - mx) * 1.44269504088896f);
        accS[nt][r] = p;
        s += p;
      }
      s += __shfl_xor(s, 1);
      s += __shfl_xor(s, 2);
      s += __shfl_xor(s, 4);
      s += __shfl_xor(s, 8);
      inv[r] = 1.0f / s;
    }
    // ---- P -> LDS (wave-private rows; wave-level ordering only) ----
    asm volatile("s_waitcnt lgkmcnt(0)" ::: "memory");  // prior chunk's Ps reads retired
    #pragma unroll
    for (int nt = 0; nt < 8; nt++)
      #pragma unroll
      for (int r = 0; r < 4; r++)
        Ps[(w * 16 + quad * 4 + r) * 136 + nt * 16 + l15] = f2bf(accS[nt][r] * inv[r]);
    asm volatile("s_waitcnt lgkmcnt(0)" ::: "memory");  // Ps writes visible to own wave
    // ---- O = P V  (COL: C[q][d])   or   O^T = V^T P^T  (ROW: C[d][q]) ----
    f32x4 accO[4] = {{0.f,0.f,0.f,0.f},{0.f,0.f,0.f,0.f},{0.f,0.f,0.f,0.f},{0.f,0.f,0.f,0.f}};
    #pragma unroll
    for (int kf = 0; kf < 4; kf++) {
      bf16x8 p = *(const bf16x8*)&Ps[(w * 16 + l15) * 136 + kf * 32 + quad * 8];
      #pragma unroll
      for (int t4 = 0; t4 < 4; t4++) {
        bf16x8 v = *(const bf16x8*)&Vt[(t4 * 16 + l15) * 136 + kf * 32 + quad * 8];
        accO[t4] = COL ? __builtin_amdgcn_mfma_f32_16x16x32_bf16(p, v, accO[t4], 0, 0, 0)
                       : __builtin_amdgcn_mfma_f32_16x16x32_bf16(v, p, accO[t4], 0, 0, 0);
      }
    }
    if (COL) {
      // lane holds (q = w*16+quad*4+r, d = t4*16+l15): 32 B-coalesced bf16 runs
      ushort* tp = tb + (size_t)fixed * 8192 + c * 4096;
      #pragma unroll
      for (int t4 = 0; t4 < 4; t4++)
        #pragma unroll
        for (int r = 0; r < 4; r++)
          tp[(w * 16 + quad * 4 + r) * 64 + t4 * 16 + l15] = f2bf(accO[t4][r]);
    } else {
      // lane holds (d = t4*16+quad*4+r, q = w*16+l15): 64 B-coalesced fp32 runs
      float* ob = out + (size_t)(b * EMB + h * 64) * SL + (size_t)fixed * 128 + c * 64 + w * 16 + l15;
      #pragma unroll
      for (int t4 = 0; t4 < 4; t4++) {
        const ushort* tr = (const ushort*)&treg[c][t4];
        #pragma unroll
        for (int r = 0; r < 4; r++)
          ob[(size_t)(t4 * 16 + quad * 4 + r) * SL] = accO[t4][r] + bf2f(tr[r]);
      }
    }
  }
}

extern "C" void kernel_launch(void* const* d_in, const int* in_sizes, int n_in,
                              void* d_out, int out_size, void* d_ws, size_t ws_size,
                              hipStream_t stream) {
  const float* x = (const float*)d_in[0];
  const float* W = (const float*)d_in[1];
  const float* bias = (const float*)d_in[2];
  float* out = (float*)d_out;
  ushort* rowQ = (ushort*)d_ws;
  ushort* xT = (ushort*)((char*)d_ws + 100663296);
  ushort* tmp = (ushort*)((char*)d_ws + 100663296);
  ushort* Wb = (ushort*)((char*)d_ws + 134217728);

  hipLaunchKernelGGL(prep, dim3(4864), dim3(256), 0, stream, W, Wb, x, xT);
  hipLaunchKernelGGL(qkv_gemm, dim3(64, 6, 2), dim3(512), 0, stream, Wb, xT, bias, rowQ);
  hipLaunchKernelGGL(attn3<1>, dim3(128, 8, 2), dim3(256), 0, stream, rowQ, tmp, out);
  hipLaunchKernelGGL(attn3<0>, dim3(128, 8, 2), dim3(256), 0, stream, rowQ, tmp, out);
}